// Round 1
// baseline (135.366 us; speedup 1.0000x reference)
//
#include <hip/hip_runtime.h>

// Problem constants (fixed by the reference setup_inputs)
constexpr int Bn = 1024;
constexpr int Nn = 128;   // pred points per batch
constexpr int Mn = 128;   // gt points per batch
constexpr int Tt = 10;    // interpolation factor
constexpr int GI = Mn * Tt;  // 1280 interpolated gt points

// d_ws accumulator layout: acc[0]=sum|pred-nearest_gt|, acc[1]=sum mask*|nearest_pred-gt|, acc[2]=sum(mask over B,M,2)

__global__ __launch_bounds__(128) void dm_main(
    const float2* __restrict__ ini,    // [B,N] of (x,y)
    const float2* __restrict__ pred,   // [B,N]
    const float2* __restrict__ gt,     // [B,M]
    const float*  __restrict__ kpm,    // [B,M]
    float* __restrict__ acc)
{
    __shared__ float2 s_interp[GI];   // 10 KB
    __shared__ float2 s_ini[Nn];      // 1 KB
    __shared__ float  s_red[3][2];

    const int b   = blockIdx.x;
    const int tid = threadIdx.x;

    // ---- stage inputs ----
    const float2 g_cur  = gt[b * Mn + tid];
    const float2 g_prev = gt[b * Mn + ((tid + Mn - 1) & (Mn - 1))];  // roll(+1): prev point
    const float2 ipt    = ini[b * Nn + tid];
    s_ini[tid] = ipt;

    // interp[m*T + t] = gt[m]*step + gt[m-1]*(1-step), step = t/10 (f32 divide, matches np)
    #pragma unroll
    for (int t = 0; t < Tt; ++t) {
        const float step = (float)t / 10.0f;
        const float om   = 1.0f - step;
        float2 v;
        v.x = __fadd_rn(__fmul_rn(g_cur.x, step), __fmul_rn(g_prev.x, om));
        v.y = __fadd_rn(__fmul_rn(g_cur.y, step), __fmul_rn(g_prev.y, om));
        s_interp[tid * Tt + t] = v;
    }
    __syncthreads();

    // ---- phase A: for n=tid, argmin over 1280 interp points (first-min tie-break) ----
    const float px = ipt.x, py = ipt.y;
    float best = 3.4e38f;
    int   bidx = 0;
    #pragma unroll 4
    for (int g = 0; g < GI; ++g) {
        const float2 q = s_interp[g];           // broadcast LDS read (all lanes same addr)
        const float dx = px - q.x;
        const float dy = py - q.y;
        const float d  = __fadd_rn(__fmul_rn(dx, dx), __fmul_rn(dy, dy));  // match np rounding
        if (d < best) { best = d; bidx = g; }
    }
    const float2 ng = s_interp[bidx];
    const float2 pr = pred[b * Nn + tid];
    float sum_p2g = fabsf(pr.x - ng.x) + fabsf(pr.y - ng.y);

    // ---- phase B: for m=tid, argmin over N pred anchor points ----
    const float gx = g_cur.x, gy = g_cur.y;
    float best2 = 3.4e38f;
    int   nidx  = 0;
    #pragma unroll 4
    for (int n = 0; n < Nn; ++n) {
        const float2 q = s_ini[n];
        const float dx = q.x - gx;
        const float dy = q.y - gy;
        const float d  = __fadd_rn(__fmul_rn(dx, dx), __fmul_rn(dy, dy));
        if (d < best2) { best2 = d; nidx = n; }
    }
    const float2 npd = pred[b * Nn + nidx];
    const float  w   = kpm[b * Mn + tid];
    float sum_g2p = w * (fabsf(npd.x - gx) + fabsf(npd.y - gy));
    float sum_m   = 2.0f * w;

    // ---- block reduction: 3 scalars over 128 threads ----
    #pragma unroll
    for (int off = 32; off > 0; off >>= 1) {
        sum_p2g += __shfl_down(sum_p2g, off);
        sum_g2p += __shfl_down(sum_g2p, off);
        sum_m   += __shfl_down(sum_m,   off);
    }
    const int wave = tid >> 6;
    if ((tid & 63) == 0) {
        s_red[0][wave] = sum_p2g;
        s_red[1][wave] = sum_g2p;
        s_red[2][wave] = sum_m;
    }
    __syncthreads();
    if (tid == 0) {
        atomicAdd(&acc[0], s_red[0][0] + s_red[0][1]);
        atomicAdd(&acc[1], s_red[1][0] + s_red[1][1]);
        atomicAdd(&acc[2], s_red[2][0] + s_red[2][1]);
    }
}

__global__ void dm_final(const float* __restrict__ acc, float* __restrict__ out)
{
    // loss = ( masked_gt2pred / (mask_sum + 1) + pred2gt_sum / (B*N*2) ) / 2
    const float inv_cnt = 1.0f / (float)(Bn * Nn * 2);   // 1/262144, exact pow2
    out[0] = (acc[1] / (acc[2] + 1.0f) + acc[0] * inv_cnt) * 0.5f;
}

extern "C" void kernel_launch(void* const* d_in, const int* in_sizes, int n_in,
                              void* d_out, int out_size, void* d_ws, size_t ws_size,
                              hipStream_t stream)
{
    const float2* ini  = (const float2*)d_in[0];  // ini_pred_poly [B,N,2]
    const float2* pred = (const float2*)d_in[1];  // pred_polys_   [B,N,2]
    const float2* gt   = (const float2*)d_in[2];  // gt_polys      [B,M,2]
    const float*  kpm  = (const float*)d_in[3];   // keyPointsMask [B,M]
    float* out = (float*)d_out;
    float* acc = (float*)d_ws;

    hipMemsetAsync(acc, 0, 3 * sizeof(float), stream);
    dm_main<<<Bn, 128, 0, stream>>>(ini, pred, gt, kpm, acc);
    dm_final<<<1, 1, 0, stream>>>(acc, out);
}

// Round 2
// 73.314 us; speedup vs baseline: 1.8464x; 1.8464x over previous
//
#include <hip/hip_runtime.h>

constexpr int Bn = 1024;
constexpr int Nn = 128;   // pred points per batch
constexpr int Mn = 128;   // gt points per batch

// Phase A insight: interp[m,t] = a + (t/10)*(b-a) with a=gt[m-1], b=gt[m], t in [0,9].
// dist(p, interp[m,t]) is quadratic in t -> evaluate only the discrete vertex.
// Per-segment constants (a, e=b-a, ee=|e|^2, -10/ee) shared across all n: precompute once.

__global__ __launch_bounds__(256) void dm_main(
    const float2* __restrict__ ini,    // [B,N]
    const float2* __restrict__ pred,   // [B,N]
    const float2* __restrict__ gt,     // [B,M]
    const float*  __restrict__ kpm,    // [B,M]
    float4* __restrict__ part)         // [B] partial sums per block
{
    __shared__ float4 s_segA[Mn];   // a.x, a.y, e.x, e.y
    __shared__ float2 s_segB[Mn];   // ee, -10*rcp(ee)
    __shared__ float2 s_ini[Nn];
    __shared__ float2 s_pred[Nn];
    __shared__ float2 s_gt[Mn];
    __shared__ float  s_red[3][4];

    const int b   = blockIdx.x;
    const int tid = threadIdx.x;

    // ---- stage + per-segment precompute (first 128 threads) ----
    if (tid < Mn) {
        const float2 cur = gt[b*Mn + tid];
        const float2 prv = gt[b*Mn + ((tid + Mn - 1) & (Mn - 1))];
        const float ex = cur.x - prv.x, ey = cur.y - prv.y;
        const float ee = fmaxf(fmaf(ex, ex, ey*ey), 1e-30f);  // guard degenerate segment
        const float nr = -10.0f * __builtin_amdgcn_rcpf(ee);
        s_segA[tid] = make_float4(prv.x, prv.y, ex, ey);
        s_segB[tid] = make_float2(ee, nr);
        s_gt[tid]   = cur;
        s_ini[tid]  = ini[b*Nn + tid];
        s_pred[tid] = pred[b*Nn + tid];
    }
    __syncthreads();

    const int lane_s = tid & 1;     // which half of the scan this thread owns
    const int n      = tid >> 1;    // point index 0..127
    const int base   = lane_s * 64;

    // ---- phase A: nearest interpolated gt point for pred point n ----
    const float2 p = s_ini[n];
    float best = 3.4e38f; int bm = 0; float bs = 0.f;
    #pragma unroll 8
    for (int i = 0; i < 64; ++i) {
        const int m = base + i;
        const float4 A  = s_segA[m];
        const float2 Bv = s_segB[m];
        const float fx = A.x - p.x, fy = A.y - p.y;
        const float fe = fmaf(fx, A.z, fy*A.w);
        const float ff = fmaf(fx, fx, fy*fy);
        float tv = fe * Bv.y;                       // vertex t = -10*fe/ee
        tv = fminf(fmaxf(rintf(tv), 0.f), 9.f);     // discrete argmin t*
        const float sp = tv * 0.1f;
        const float d  = fmaf(sp, fmaf(sp, Bv.x, fe + fe), ff);
        if (d < best) { best = d; bm = m; bs = sp; }
    }
    {   // merge the two half-scans (lex tie-break on segment index)
        const float od = __shfl_xor(best, 1);
        const int   om = __shfl_xor(bm, 1);
        const float os = __shfl_xor(bs, 1);
        if (od < best || (od == best && om < bm)) { best = od; bm = om; bs = os; }
    }
    float sum_p2g = 0.f;
    if (lane_s == 0) {
        const float4 A = s_segA[bm];
        const float ngx = fmaf(bs, A.z, A.x);
        const float ngy = fmaf(bs, A.w, A.y);
        const float2 pr = s_pred[n];
        sum_p2g = fabsf(pr.x - ngx) + fabsf(pr.y - ngy);
    }

    // ---- phase B: nearest pred-anchor for gt point m=n ----
    const float2 g = s_gt[n];
    float best2 = 3.4e38f; int ni = 0;
    #pragma unroll 8
    for (int i = 0; i < 64; ++i) {
        const int j = base + i;
        const float2 q = s_ini[j];
        const float dx = q.x - g.x, dy = q.y - g.y;
        const float d = fmaf(dx, dx, dy*dy);
        if (d < best2) { best2 = d; ni = j; }
    }
    {
        const float od = __shfl_xor(best2, 1);
        const int   oi = __shfl_xor(ni, 1);
        if (od < best2 || (od == best2 && oi < ni)) { best2 = od; ni = oi; }
    }
    float sum_g2p = 0.f, sum_m = 0.f;
    if (lane_s == 0) {
        const float  w   = kpm[b*Mn + n];
        const float2 np_ = s_pred[ni];
        sum_g2p = w * (fabsf(np_.x - g.x) + fabsf(np_.y - g.y));
        sum_m   = 2.0f * w;
    }

    // ---- block reduction: 3 scalars over 256 threads -> one float4 store ----
    #pragma unroll
    for (int off = 32; off > 0; off >>= 1) {
        sum_p2g += __shfl_down(sum_p2g, off);
        sum_g2p += __shfl_down(sum_g2p, off);
        sum_m   += __shfl_down(sum_m,   off);
    }
    const int wv = tid >> 6;
    if ((tid & 63) == 0) { s_red[0][wv] = sum_p2g; s_red[1][wv] = sum_g2p; s_red[2][wv] = sum_m; }
    __syncthreads();
    if (tid == 0) {
        part[b] = make_float4(s_red[0][0] + s_red[0][1] + s_red[0][2] + s_red[0][3],
                              s_red[1][0] + s_red[1][1] + s_red[1][2] + s_red[1][3],
                              s_red[2][0] + s_red[2][1] + s_red[2][2] + s_red[2][3], 0.f);
    }
}

__global__ __launch_bounds__(1024) void dm_final(const float4* __restrict__ part,
                                                 float* __restrict__ out)
{
    __shared__ float s_red[3][16];
    const int tid = threadIdx.x;
    const float4 v = part[tid];
    float a = v.x, c = v.y, m = v.z;
    #pragma unroll
    for (int off = 32; off > 0; off >>= 1) {
        a += __shfl_down(a, off); c += __shfl_down(c, off); m += __shfl_down(m, off);
    }
    const int wv = tid >> 6;
    if ((tid & 63) == 0) { s_red[0][wv] = a; s_red[1][wv] = c; s_red[2][wv] = m; }
    __syncthreads();
    if (tid == 0) {
        float A = 0.f, C = 0.f, M = 0.f;
        #pragma unroll
        for (int i = 0; i < 16; ++i) { A += s_red[0][i]; C += s_red[1][i]; M += s_red[2][i]; }
        // loss = ( masked_gt2pred/(mask_sum+1) + pred2gt_sum/(B*N*2) ) / 2
        out[0] = (C / (M + 1.0f) + A * (1.0f / 262144.0f)) * 0.5f;
    }
}

extern "C" void kernel_launch(void* const* d_in, const int* in_sizes, int n_in,
                              void* d_out, int out_size, void* d_ws, size_t ws_size,
                              hipStream_t stream)
{
    const float2* ini  = (const float2*)d_in[0];
    const float2* pred = (const float2*)d_in[1];
    const float2* gt   = (const float2*)d_in[2];
    const float*  kpm  = (const float*)d_in[3];
    float*  out  = (float*)d_out;
    float4* part = (float4*)d_ws;   // 1024 * 16 B, fully rewritten every call

    dm_main<<<Bn, 256, 0, stream>>>(ini, pred, gt, kpm, part);
    dm_final<<<1, 1024, 0, stream>>>(part, out);
}